// Round 1
// 316.530 us; speedup vs baseline: 1.1033x; 1.1033x over previous
//
#include <hip/hip_runtime.h>

typedef __bf16 bf16x8 __attribute__((ext_vector_type(8)));
typedef __bf16 bf16x4 __attribute__((ext_vector_type(4)));
typedef float f32x4 __attribute__((ext_vector_type(4)));
typedef unsigned long long u64;

#define NCH 8            // row-chunks per recurrence
#define CELLS 16         // rows per chunk
#define NG 256           // 4 gates * 64 units
#define L2E 1.44269504089f
#define RDEPTH 8                        // ring depth (tag mod 8)
#define NLINK (16 * 7)                  // (g, producer ch 0..6)
#define RING_U64 (NLINK * RDEPTH * 64)  // 448 KiB
#define PROG_OFF (RING_U64 * 8)         // byte offset of progress flags

__device__ __forceinline__ unsigned short f2bfbits(float f) {
  __bf16 b = (__bf16)f;
  return __builtin_bit_cast(unsigned short, b);
}
__device__ __forceinline__ float sigm2(float x) {  // arg pre-scaled by log2e
  return __builtin_amdgcn_rcpf(1.f + __builtin_amdgcn_exp2f(-x));
}
__device__ __forceinline__ float tanh2(float x) {  // arg pre-scaled by 2*log2e
  return 1.f - 2.f * __builtin_amdgcn_rcpf(1.f + __builtin_amdgcn_exp2f(x));
}
// LDS-only barrier: vmcnt stays in flight (out stores, x prefetch, ring ops)
__device__ __forceinline__ void barrier_lds() {
  asm volatile("s_waitcnt lgkmcnt(0)" ::: "memory");
  __builtin_amdgcn_s_barrier();
}
// 16B-granule XOR swizzles. h rows are 128B bf16; buffer row r holds chunk
// row r-1 (row 0 = upstream guard; row0 swizzle is identity -> linear copy).
__device__ __forceinline__ int hix(int row, int byteoff) {
  return row * 128 + (byteoff ^ ((row & 7) << 4));
}
__device__ __forceinline__ int cix(int row, int q) {  // 64-f32 rows
  return row * 64 + ((((q >> 2) ^ (row & 7)) << 2) | (q & 3));
}

// ROW-partitioned 2D-LSTM pipeline; WAVE-SPECIALIZED single-barrier step.
// Block = (chunk ch, recurrence g), 512 thr = 8 waves (2/SIMD):
//   waves 0-3 (compute): post-barrier critical region = {h(d-1) reads (rows
//     lo16/lo16+1 of 17-row guard-folded dbuf), c reads, h-sum, 16 h@Wr MFMA
//     (dual hi/lo acc chains), LSTM epilogue, publish, state/out writes};
//     then barrier-shadow tail = {x(d+1) frag prefetch + 8 x@Wk+b MFMA for
//     NEXT step}. h_ul/c_ul are REGISTER-CARRIED from prev step's h_up/c_up
//     (identical values) -- no d-2 buffer, no guard selects.
//   waves 4-7 (helper): stage x(d+2)->xt[3], prefetch x(d+3); wave 4 copies
//     ring guard tag d into row 0 of the write buffers and macro-polls tags
//     d+1..d+4 every 4 steps into gbh/gbc, updating prog.
__global__ __launch_bounds__(512, 1) void mdrnn_kernel(
    const float* __restrict__ x, const float* __restrict__ Wk,
    const float* __restrict__ Wr, const float* __restrict__ bias,
    float* __restrict__ out, char* __restrict__ ws) {
  __shared__ __align__(16) unsigned char xt[3][CELLS * 128];   // 6 KiB
  __shared__ __align__(16) unsigned char hbuf[2][17 * 128];    // 4.25 KiB
  __shared__ __align__(16) float cbuf[2][17 * 64];             // 8.5 KiB
  __shared__ __align__(16) unsigned char gbh[8 * 128];         // 1 KiB
  __shared__ __align__(16) float gbc[8 * 64];                  // 2 KiB

  u64* __restrict__ ring = (u64*)ws;
  int* __restrict__ prog = (int*)(ws + PROG_OFF);  // 16-int (64B) stride

  const int tid = threadIdx.x;
  const bool isComp = (tid < 256);
  const int L = tid & 63;
  const int lo16 = L & 15;
  const int hi16 = L >> 4;
  const int u = ((tid >> 6) & 3) * 16 + lo16;  // compute: unit index
  const int hm0 = (tid >> 4) & 15;             // helper: staged row
  const int hq16 = tid & 15;                   // helper: channel quad
  const int hw = (tid >> 6) & 3;               // helper wave id (tid>=256)

  const int ch = blockIdx.x >> 4;   // bx%8 == g%8 -> chain on one XCD
  const int g = blockIdx.x & 15;
  const int f = g >> 2;
  const int bb = g & 3;
  const int fh = (f >> 1) & 1;
  const int fw = f & 1;
  const int R0 = ch * CELLS;
  const int D1 = R0 + 142;
  const int linkDn = g * 7 + ch - 1;
  const int linkUp = g * 7 + ch;

  for (int i = tid; i < 3 * CELLS * 32; i += 512) ((int*)xt)[i] = 0;
  for (int i = tid; i < 2 * 17 * 32; i += 512) ((int*)hbuf)[i] = 0;
  for (int i = tid; i < 2 * 17 * 64; i += 512) ((float*)cbuf)[i] = 0.f;
  for (int i = tid; i < 8 * 32; i += 512) ((int*)gbh)[i] = 0;
  for (int i = tid; i < 8 * 64; i += 512) gbc[i] = 0.f;

  // ---- compute-wave constants ----
  float bsc[4];
  bf16x8 wkh[4][2], wrh[4][2], wrl[4][2];
  int oidx[4];
  int oStep = 0, cbase = 0;
  int o_hu0 = 0, o_hu1 = 0, o_hl0 = 0, o_hl1 = 0;
  int o_cu[4] = {0, 0, 0, 0}, o_cl[4] = {0, 0, 0, 0}, o_hw[4] = {0, 0, 0, 0};
  if (isComp) {
    const float* Wkf = Wk + f * (64 * NG);
    const float* Wrf = Wr + f * (64 * NG);
#pragma unroll
    for (int t = 0; t < 4; ++t) {
      const float st = (t == 2) ? (2.f * L2E) : L2E;
      bsc[t] = bias[f * NG + t * 64 + u] * st;
#pragma unroll
      for (int kt = 0; kt < 2; ++kt)
#pragma unroll
        for (int jj = 0; jj < 8; ++jj) {
          int k = kt * 32 + hi16 * 8 + jj;
          float vk = Wkf[k * NG + t * 64 + u] * st;
          wkh[t][kt][jj] = (__bf16)vk;
          float vr = Wrf[k * NG + t * 64 + u] * st;
          __bf16 vh = (__bf16)vr;
          wrh[t][kt][jj] = vh;
          wrl[t][kt][jj] = (__bf16)(vr - (float)vh);
        }
    }
    const int ccStep = fw ? -1 : 1;
#pragma unroll
    for (int j = 0; j < 4; ++j) {
      int ro = R0 + hi16 * 4 + j;
      int rr = fh ? 127 - ro : ro;
      int c0 = R0 - ro;
      oidx[j] = ((bb * 128 + rr) * 128 + (fw ? 127 - c0 : c0)) * NG + f * 64 + u;
      int lm = hi16 * 4 + j;
      o_cu[j] = cix(lm, u);       // c_up   (buffer row lm = chunk row lm-1)
      o_cl[j] = cix(lm + 1, u);   // c_left AND c write (buffer row lm+1)
      o_hw[j] = hix(lm + 1, u * 2);
    }
    oStep = ccStep * NG;
    cbase = -hi16 * 4;
    o_hu0 = hix(lo16, hi16 * 16);       // h_up  (buffer row lo16)
    o_hu1 = hix(lo16, 64 + hi16 * 16);
    o_hl0 = hix(lo16 + 1, hi16 * 16);   // h_left (buffer row lo16+1)
    o_hl1 = hix(lo16 + 1, 64 + hi16 * 16);
  }
  const int o_ax0 = hix(lo16, hi16 * 16);
  const int o_ax1 = hix(lo16, 64 + hi16 * 16);

  // ---- helper-wave x addressing ----
  const int ccStepH = fw ? -1 : 1;
  const int rx = R0 + hm0;
  const int rrx = fh ? 127 - rx : rx;
  int cx = R0 - rx;
  int xidx = ((bb * 128 + rrx) * 128 + (fw ? 127 - cx : cx)) * 64 + hq16 * 4;
  const int xStep = ccStepH * 64;
  float4 px;
  bool pxv = false;
  auto ldg = [&]() {
    pxv = ((unsigned)cx <= 127u);
    px = make_float4(0.f, 0.f, 0.f, 0.f);
    if (pxv) px = *(const float4*)(x + xidx);
    xidx += xStep;
    ++cx;
  };
  auto stx = [&](unsigned char* buf) {
    if (pxv) {
      bf16x4 pk;
      pk[0] = (__bf16)px.x; pk[1] = (__bf16)px.y;
      pk[2] = (__bf16)px.z; pk[3] = (__bf16)px.w;
      *(bf16x4*)(buf + hix(hm0, hq16 * 8)) = pk;
    }
  };

  __syncthreads();  // zero-init visible

  if (!isComp) {
    ldg();  // px = x(R0)
    stx(&xt[R0 % 3][0]);
    ldg();  // px = x(R0+1)
    stx(&xt[(R0 + 1) % 3][0]);
    ldg();  // px = x(R0+2)
    // pre-loop poll (helper wave 0): tags R0-1 and R0; fold R0-1 into row 0
    if (hw == 0 && ch > 0) {
#pragma unroll
      for (int k = 0; k < 2; ++k) {
        const int q = R0 - 1 + k;
        u64* src = ring + ((linkDn * RDEPTH + (q & 7)) << 6) + L;
        u64 v;
        int spin = 0;
        for (;;) {
          v = __hip_atomic_load(src, __ATOMIC_RELAXED, __HIP_MEMORY_SCOPE_AGENT);
          if ((unsigned short)(v >> 48) == (unsigned short)q ||
              spin >= (1 << 22))
            break;
          ++spin;
          __builtin_amdgcn_s_sleep(2);
        }
        *(unsigned short*)(gbh + (q & 7) * 128 + L * 2) =
            (unsigned short)(v >> 32);
        gbc[(q & 7) * 64 + L] = __uint_as_float((unsigned)v);
        if (k == 0) {  // guard tag R0-1 -> row 0 of the "previous" buffers
          *(unsigned short*)(&hbuf[(R0 + 1) & 1][0] + L * 2) =
              (unsigned short)(v >> 32);
          cbuf[(R0 + 1) & 1][L] = __uint_as_float((unsigned)v);
        }
      }
      if (L == 0)
        __hip_atomic_store(&prog[linkDn * 16], R0, __ATOMIC_RELAXED,
                           __HIP_MEMORY_SCOPE_AGENT);
    }
  }
  __syncthreads();

  // ---- rotating state (all threads; uniform) ----
  unsigned char* hW = &hbuf[R0 & 1][0];
  unsigned char* hP = &hbuf[(R0 + 1) & 1][0];
  float* cW = &cbuf[R0 & 1][0];
  float* cP = &cbuf[(R0 + 1) & 1][0];
  unsigned char* xr0 = &xt[(R0 + 1) % 3][0];  // read x(d+1) at step d
  unsigned char* xr1 = &xt[(R0 + 2) % 3][0];  // helper writes x(d+2) here
  unsigned char* xr2 = &xt[R0 % 3][0];
  int gOff = (R0 & 7) * 128;

  // ---- compute prologue: accA(R0) in advance; zero carried ul state ----
  f32x4 accA[4];
  bf16x8 hxp0, hxp1;  // carried h_ul = prev step's h_up (same LDS bits)
  float puv[4];       // carried c_ul = prev step's c_up
  int gateSeen = 0;
  if (isComp) {
#pragma unroll
    for (int e = 0; e < 8; ++e) { hxp0[e] = (__bf16)0.f; hxp1[e] = (__bf16)0.f; }
#pragma unroll
    for (int j = 0; j < 4; ++j) puv[j] = 0.f;
    bf16x8 a0 = *(const bf16x8*)(xr2 + o_ax0);  // x(R0), staged pre-loop
    bf16x8 a1 = *(const bf16x8*)(xr2 + o_ax1);
#pragma unroll
    for (int t = 0; t < 4; ++t) {
      accA[t] = (f32x4){bsc[t], bsc[t], bsc[t], bsc[t]};
      accA[t] = __builtin_amdgcn_mfma_f32_16x16x32_bf16(a0, wkh[t][0], accA[t], 0, 0, 0);
      accA[t] = __builtin_amdgcn_mfma_f32_16x16x32_bf16(a1, wkh[t][1], accA[t], 0, 0, 0);
    }
    __builtin_amdgcn_s_setprio(1);  // compute waves favored over helpers
  }

  for (int d = R0; d <= D1; ++d) {
    if (isComp) {
      // ---- post-barrier critical region ----
      bf16x8 hu0 = *(const bf16x8*)(hP + o_hu0);
      bf16x8 hu1 = *(const bf16x8*)(hP + o_hu1);
      bf16x8 hl0 = *(const bf16x8*)(hP + o_hl0);
      bf16x8 hl1 = *(const bf16x8*)(hP + o_hl1);
      float pu[4], pl[4];
#pragma unroll
      for (int j = 0; j < 4; ++j) { pu[j] = cP[o_cu[j]]; pl[j] = cP[o_cl[j]]; }

      const bool pub = (ch < NCH - 1) && (d >= R0 + 15);
      if (pub && d >= R0 + 23 && gateSeen < d - 8)  // early gate refresh
        gateSeen = __hip_atomic_load(&prog[linkUp * 16], __ATOMIC_RELAXED,
                                     __HIP_MEMORY_SCOPE_AGENT);

      // h-sum A-fragments (h_ul carried in registers from prev step)
      bf16x8 ah0, ah1;
#pragma unroll
      for (int e = 0; e < 8; ++e) {
        ah0[e] = (__bf16)((float)hu0[e] + (float)hl0[e] + (float)hxp0[e]);
        ah1[e] = (__bf16)((float)hu1[e] + (float)hl1[e] + (float)hxp1[e]);
      }
      hxp0 = hu0;
      hxp1 = hu1;
      float csj[4];
#pragma unroll
      for (int j = 0; j < 4; ++j) { csj[j] = pu[j] + pl[j] + puv[j]; puv[j] = pu[j]; }

      // ---- h@Wr MFMA: dual hi/lo accumulators (2-deep chains) ----
      f32x4 aH[4], aL[4];
#pragma unroll
      for (int t = 0; t < 4; ++t) { aH[t] = (f32x4){0.f, 0.f, 0.f, 0.f}; aL[t] = (f32x4){0.f, 0.f, 0.f, 0.f}; }
#pragma unroll
      for (int t = 0; t < 4; ++t)
        aH[t] = __builtin_amdgcn_mfma_f32_16x16x32_bf16(ah0, wrh[t][0], aH[t], 0, 0, 0);
#pragma unroll
      for (int t = 0; t < 4; ++t)
        aL[t] = __builtin_amdgcn_mfma_f32_16x16x32_bf16(ah0, wrl[t][0], aL[t], 0, 0, 0);
#pragma unroll
      for (int t = 0; t < 4; ++t)
        aH[t] = __builtin_amdgcn_mfma_f32_16x16x32_bf16(ah1, wrh[t][1], aH[t], 0, 0, 0);
#pragma unroll
      for (int t = 0; t < 4; ++t)
        aL[t] = __builtin_amdgcn_mfma_f32_16x16x32_bf16(ah1, wrl[t][1], aL[t], 0, 0, 0);

      // ---- epilogue: LSTM, publish (top row first), state/out writes ----
#pragma unroll
      for (int jj = 0; jj < 4; ++jj) {
        const int j = 3 - jj;
        const int lm = hi16 * 4 + j;
        const int r = R0 + lm;
        const int cj = cbase - j;
        const bool ok = ((unsigned)cj <= 127u);
        const float inv = (cj == 0 || r == 0) ? 1.f : (1.f / 3.f);
        const float cpj = csj[j] * inv;
        const float zi = accA[0][j] + inv * (aH[0][j] + aL[0][j]);
        const float zf = accA[1][j] + inv * (aH[1][j] + aL[1][j]);
        const float zg = accA[2][j] + inv * (aH[2][j] + aL[2][j]);
        const float zo = accA[3][j] + inv * (aH[3][j] + aL[3][j]);
        float cn = sigm2(zf) * cpj + sigm2(zi) * tanh2(zg);
        float hn = sigm2(zo) * tanh2(2.f * L2E * cn);
        if (pub && lm == CELLS - 1) {
          if (d >= R0 + 23 && gateSeen < d - 8) {  // ring-wrap gate (backstop)
            int spin = 0;
            do {
              gateSeen = __hip_atomic_load(&prog[linkUp * 16], __ATOMIC_RELAXED,
                                           __HIP_MEMORY_SCOPE_AGENT);
            } while (gateSeen < d - 8 && ++spin < (1 << 22));
          }
          u64 v = ((u64)(unsigned short)d << 48) | ((u64)f2bfbits(hn) << 32) |
                  (u64)__float_as_uint(cn);
          u64* dst = ring + ((linkUp * RDEPTH + (d & 7)) << 6) + u;
          __hip_atomic_store(dst, v, __ATOMIC_RELAXED,
                             __HIP_MEMORY_SCOPE_AGENT);
        }
        cW[o_cl[j]] = ok ? cn : 0.f;
        *(unsigned short*)(hW + o_hw[j]) =
            ok ? f2bfbits(hn) : (unsigned short)0;
        if (ok) out[oidx[j]] = hn;
      }
#pragma unroll
      for (int j = 0; j < 4; ++j) oidx[j] += oStep;
      ++cbase;

      // ---- barrier-shadow tail: x(d+1) frags + accA for next step ----
      bf16x8 a0 = *(const bf16x8*)(xr0 + o_ax0);
      bf16x8 a1 = *(const bf16x8*)(xr0 + o_ax1);
#pragma unroll
      for (int t = 0; t < 4; ++t) {
        accA[t] = (f32x4){bsc[t], bsc[t], bsc[t], bsc[t]};
        accA[t] = __builtin_amdgcn_mfma_f32_16x16x32_bf16(a0, wkh[t][0], accA[t], 0, 0, 0);
        accA[t] = __builtin_amdgcn_mfma_f32_16x16x32_bf16(a1, wkh[t][1], accA[t], 0, 0, 0);
      }
    } else {
      // ---- helpers: guard-copy (wave 4), stage x(d+2), prefetch, poll ----
      if (hw == 0 && ch > 0) {  // ring guard tag d -> row 0 of write buffers
        *(unsigned short*)(hW + L * 2) =
            *(const unsigned short*)(gbh + gOff + L * 2);
        cW[L] = gbc[(gOff >> 1) + L];
      }
      stx(xr1);  // x(d+2) -> xt[(d+2)%3]
      ldg();     // px = x(d+3)

      if (((d - R0) & 3) == 0 && ch > 0 && hw == 0) {
        u64 pv[4];
        const u64* ps[4];
        bool live[4];
#pragma unroll
        for (int k = 0; k < 4; ++k) {
          const int q = d + 1 + k;
          live[k] = (q <= R0 + 126);
          ps[k] = ring + ((linkDn * RDEPTH + (q & 7)) << 6) + L;
          pv[k] = live[k] ? __hip_atomic_load(ps[k], __ATOMIC_RELAXED,
                                              __HIP_MEMORY_SCOPE_AGENT)
                          : 0;
        }
#pragma unroll
        for (int k = 0; k < 4; ++k) {
          const int q = d + 1 + k;
          if (!live[k]) continue;
          int spin = 0;
          while ((unsigned short)(pv[k] >> 48) != (unsigned short)q &&
                 spin < (1 << 22)) {
            ++spin;
            __builtin_amdgcn_s_sleep(1);
            pv[k] = __hip_atomic_load(ps[k], __ATOMIC_RELAXED,
                                      __HIP_MEMORY_SCOPE_AGENT);
          }
          *(unsigned short*)(gbh + (q & 7) * 128 + L * 2) =
              (unsigned short)(pv[k] >> 32);
          gbc[(q & 7) * 64 + L] = __uint_as_float((unsigned)pv[k]);
        }
        if (L == 0)
          __hip_atomic_store(&prog[linkDn * 16], min(d + 4, R0 + 126),
                             __ATOMIC_RELAXED, __HIP_MEMORY_SCOPE_AGENT);
      }
    }

    // rotate buffers (uniform, cheap: swaps + masked add, no % math)
    {
      unsigned char* t0 = xr0; xr0 = xr1; xr1 = xr2; xr2 = t0;
      unsigned char* t1 = hW; hW = hP; hP = t1;
      float* t2 = cW; cW = cP; cP = t2;
      gOff = (gOff + 128) & 1023;
    }
    barrier_lds();  // single barrier: all LDS writes -> next step's reads
  }
}

extern "C" void kernel_launch(void* const* d_in, const int* in_sizes, int n_in,
                              void* d_out, int out_size, void* d_ws, size_t ws_size,
                              hipStream_t stream) {
  const float* x = (const float*)d_in[0];
  const float* Wk = (const float*)d_in[1];
  const float* Wr = (const float*)d_in[2];
  const float* b = (const float*)d_in[3];
  float* out = (float*)d_out;
  // reset ring tags + progress flags every launch (graph-replay determinism)
  hipMemsetAsync(d_ws, 0, PROG_OFF + NLINK * 16 * sizeof(int), stream);
  hipLaunchKernelGGL(mdrnn_kernel, dim3(128), dim3(512), 0, stream, x, Wk, Wr,
                     b, out, (char*)d_ws);
}